// Round 8
// baseline (142.638 us; speedup 1.0000x reference)
//
#include <hip/hip_runtime.h>
#include <math.h>

#define BB 8
#define HH 256
#define WW 256
#define NPIX (BB*HH*WW)
#define NROWS (BB*HH)   // 2048

// ws layout (byte offsets):
//   [0]    double   bsum[8]       per-batch sum(phi*prob)        (atomic f64)
//   [64]   double   gsum          sum over batches of S_b/denom  (atomic f64)
//   [72]   unsigned bmax[8]       per-batch max dist, float bits (atomicMax)
//   [104]  int      bfg[8]        per-batch has-fg               (atomicOr)
//   [136]  unsigned cnt[8]        per-batch finished-block count
//   [168]  unsigned gcnt          finished-batch count
//   [256]  unsigned fg_words[8][8][256]  column fg bitmasks (64 KB):
//                                 word w of col j, bit r = row 32*w+r
// All control words zeroed by maskbuild block 0 (stream-ordered before edt_row;
// kernel-boundary release makes them visible). NO fences anywhere: all
// cross-block communication is device-scope atomics (coherent per G12/G16).

// k1: build column bitmasks, coalesced. Block = (batch, 32-row band).
__global__ void maskbuild(const int* __restrict__ tgt,
                          unsigned* __restrict__ fg_words,
                          unsigned* __restrict__ ctrl) {
    if (blockIdx.x == 0 && threadIdx.x < 48) ctrl[threadIdx.x] = 0u;  // 43 words used
    int blk = blockIdx.x;            // b*8 + band
    int b = blk >> 3, band = blk & 7;
    int j = threadIdx.x;
    const int* base = tgt + b * (HH * WW) + (band * 32) * WW + j;
    unsigned bits = 0;
    #pragma unroll
    for (int r = 0; r < 32; ++r)
        bits |= (base[r * WW] != 0 ? 1u : 0u) << r;
    fg_words[b * 2048 + band * 256 + j] = bits;
}

// k2: one block per (b,i) row — R6's proven EDT core (masks global->reg),
// fence-free fused reduction tail (atomics + consume-ordering only).
__global__ void edt_row(const unsigned* __restrict__ fg_words,
                        const float* __restrict__ pred,
                        double* __restrict__ bsum,
                        double* __restrict__ gsum,
                        unsigned* __restrict__ bmax,
                        int* __restrict__ bfg,
                        unsigned* __restrict__ cnt,
                        unsigned* __restrict__ gcnt,
                        float* __restrict__ out) {
    __shared__ float sB[3 * WW];          // dist_to_bg^2 at WW+jp, 1e30 pads
    __shared__ float sF[3 * WW];          // dist_to_fg^2
    __shared__ float wmax[4];
    __shared__ double wsum[4];
    __shared__ int wfg[4];

    int row = blockIdx.x;                 // b*HH + i
    int b = row >> 8, i = row & 255;
    int j = threadIdx.x;

    float x = pred[row * WW + j];         // independent, issue early

    // own-column mask words, coalesced across j for each w
    const unsigned* mb = fg_words + b * 2048;
    unsigned mw[8];
    #pragma unroll
    for (int w = 0; w < 8; ++w) mw[w] = mb[w * 256 + j];

    // vertical distances for (i, col j) from the 256-bit column mask (exact)
    const int BIGI = 1 << 20;
    int pF = -BIGI, pB = -BIGI, nF = BIGI, nB = BIGI;
    #pragma unroll
    for (int w = 0; w < 4; ++w) {
        unsigned long long v = (unsigned long long)mw[2 * w]
                             | ((unsigned long long)mw[2 * w + 1] << 32);
        unsigned long long g = ~v;
        int d = i - 64 * w;               // my bit position within this word
        unsigned long long bf = (d >= 63) ? v : ((d < 0) ? 0ull : (v & (~0ull >> (63 - d))));
        unsigned long long bb = (d >= 63) ? g : ((d < 0) ? 0ull : (g & (~0ull >> (63 - d))));
        if (bf) pF = 64 * w + 63 - __builtin_clzll(bf);   // w ascending => max
        if (bb) pB = 64 * w + 63 - __builtin_clzll(bb);
        unsigned long long af = (d <= 0) ? v : ((d > 63) ? 0ull : (v & (~0ull << d)));
        unsigned long long ab = (d <= 0) ? g : ((d > 63) ? 0ull : (g & (~0ull << d)));
        if (af) nF = min(nF, 64 * w + __builtin_ctzll(af));
        if (ab) nB = min(nB, 64 * w + __builtin_ctzll(ab));
    }
    int gF = min(min(i - pF, nF - i), 512);   // dist to nearest fg (0 if own fg)
    int gB = min(min(i - pB, nB - i), 512);   // dist to nearest bg
    bool isFg = (gF == 0);
    unsigned long long fgb = __ballot(isFg);

    float fF = (float)gF, fB = (float)gB;
    sF[j] = 1e30f; sF[2 * WW + j] = 1e30f; sF[WW + j] = fF * fF;
    sB[j] = 1e30f; sB[2 * WW + j] = 1e30f; sB[WW + j] = fB * fB;
    __syncthreads();

    // pruned exact 1D EDT over the OPPOSITE class (own-class dist is 0)
    const float* sp = isFg ? sB : sF;
    float m = isFg ? fB * fB : fF * fF;
    int idx = WW + j;
    for (int k = 1; k < WW; ++k) {
        float k2 = (float)(k * k);
        if (k2 >= m) break;               // exact termination (monotone offsets)
        m = fminf(m, sp[idx - k] + k2);
        m = fminf(m, sp[idx + k] + k2);
    }
    float dist = sqrtf(m);
    float phi = isFg ? -dist : dist;
    float prob = 1.0f / (1.0f + expf(-x));
    double sd = (double)(phi * prob);
    float mx = dist;

    #pragma unroll
    for (int off = 32; off; off >>= 1) {
        mx = fmaxf(mx, __shfl_down(mx, off));
        sd += __shfl_down(sd, off);
    }
    int wid = j >> 6;
    if ((j & 63) == 0) { wmax[wid] = mx; wsum[wid] = sd; wfg[wid] = (fgb != 0ull); }
    __syncthreads();
    if (j != 0) return;

    // ---- fence-free tail: device-scope atomics, completion via consume ----
    float M = fmaxf(fmaxf(wmax[0], wmax[1]), fmaxf(wmax[2], wmax[3]));
    double S = wsum[0] + wsum[1] + wsum[2] + wsum[3];
    int F = wfg[0] | wfg[1] | wfg[2] | wfg[3];

    double oS = atomicAdd(&bsum[b], S);
    unsigned oM = atomicMax(&bmax[b], __float_as_uint(M));  // dist>=0: bits monotone
    int oF = atomicOr(&bfg[b], F);
    unsigned long long uS = __double_as_longlong(oS);
    asm volatile("" :: "v"(uS), "v"(oM), "v"(oF));  // atomics completed at coherent point
    unsigned oc = atomicAdd(&cnt[b], 1u);
    if (oc == (unsigned)(HH - 1)) {
        // all 256 row-blocks of batch b have completed their accumulations
        double Sb = atomicAdd(&bsum[b], 0.0);       // coherent identity reads
        unsigned Mb = atomicMax(&bmax[b], 0u);
        int Fb = atomicOr(&bfg[b], 0);
        double term = Fb ? Sb / ((double)__uint_as_float(Mb) + 1e-8) : 0.0;
        double oG = atomicAdd(gsum, term);
        unsigned long long uG = __double_as_longlong(oG);
        asm volatile("" :: "v"(uG));
        unsigned og = atomicAdd(gcnt, 1u);
        if (og == (unsigned)(BB - 1)) {
            double tot = atomicAdd(gsum, 0.0);      // all 8 terms complete
            out[0] = (float)(tot / (double)NPIX);
        }
    }
}

extern "C" void kernel_launch(void* const* d_in, const int* in_sizes, int n_in,
                              void* d_out, int out_size, void* d_ws, size_t ws_size,
                              hipStream_t stream) {
    const float* pred = (const float*)d_in[0];
    const int* tgt = (const int*)d_in[1];
    float* out = (float*)d_out;

    char* ws = (char*)d_ws;
    double* bsum = (double*)ws;                    // 8 doubles
    double* gsum = (double*)(ws + 64);             // 1 double
    unsigned* bmax = (unsigned*)(ws + 72);         // 8 u32
    int* bfg = (int*)(ws + 104);                   // 8 i32
    unsigned* cnt = (unsigned*)(ws + 136);         // 8 u32
    unsigned* gcnt = (unsigned*)(ws + 168);        // 1 u32
    unsigned* ctrl = (unsigned*)ws;                // covers all of the above (43 words)
    unsigned* fg_words = (unsigned*)(ws + 256);    // 16384 u32 (64 KB)

    maskbuild<<<64, 256, 0, stream>>>(tgt, fg_words, ctrl);
    edt_row<<<NROWS, WW, 0, stream>>>(fg_words, pred, bsum, gsum, bmax, bfg,
                                      cnt, gcnt, out);
}

// Round 9
// 65.117 us; speedup vs baseline: 2.1905x; 2.1905x over previous
//
#include <hip/hip_runtime.h>
#include <math.h>

#define BB 8
#define HH 256
#define WW 256
#define NPIX (BB*HH*WW)
#define NROWS (BB*HH)   // 2048

// ws layout (byte offsets), every slot written before read (no init kernel):
//   [0]      float    part_max[2048]   per-row max dist
//   [8192]   double   part_sum[2048]   per-row sum(phi*prob)
//   [24576]  int      part_fg[2048]    per-row has-fg flag
//   [32768]  unsigned fg_words[8][8][256]  column fg bitmasks: word w of col j,
//                                          bit r = row 32*w + r  (64 KB total)
//
// Structure note (R7/R8 lesson): cross-block reduction MUST stay a separate
// tiny kernel. Fusing it into edt_row via __threadfence (R7: 59.7us kernel)
// or returned-value device atomics (R8: 88us kernel) costs 10-30x the ~2us
// a third graph node costs — kernel-boundary release is the cheap coherence
// mechanism on non-coherent per-XCD L2s.

// k1: build column bitmasks, fully coalesced. Block = (batch, 32-row band).
__global__ void maskbuild(const int* __restrict__ tgt,
                          unsigned* __restrict__ fg_words) {
    int blk = blockIdx.x;            // b*8 + band
    int b = blk >> 3, band = blk & 7;
    int j = threadIdx.x;
    const int* base = tgt + b * (HH * WW) + (band * 32) * WW + j;
    unsigned bits = 0;
    #pragma unroll
    for (int r = 0; r < 32; ++r)
        bits |= (base[r * WW] != 0 ? 1u : 0u) << r;
    fg_words[b * 2048 + band * 256 + j] = bits;
}

// k2: one block per (b,i) row — R6's proven core; mask words global->reg
// (thread j only ever consumed its own column's words, LDS staging was waste).
__global__ void edt_row(const unsigned* __restrict__ fg_words,
                        const float* __restrict__ pred,
                        float* __restrict__ part_max,
                        double* __restrict__ part_sum,
                        int* __restrict__ part_fg) {
    __shared__ float sB[3 * WW];          // dist_to_bg^2 at WW+jp, 1e30 pads
    __shared__ float sF[3 * WW];          // dist_to_fg^2
    __shared__ float wmax[4];
    __shared__ double wsum[4];
    __shared__ int wfg[4];

    int row = blockIdx.x;                 // b*HH + i
    int b = row >> 8, i = row & 255;
    int j = threadIdx.x;

    float x = pred[row * WW + j];         // independent, issue early

    // own-column mask words, coalesced across j for each w
    const unsigned* mb = fg_words + b * 2048;
    unsigned mw[8];
    #pragma unroll
    for (int w = 0; w < 8; ++w) mw[w] = mb[w * 256 + j];

    // vertical distances for (i, col j) from the 256-bit column mask (exact)
    const int BIGI = 1 << 20;
    int pF = -BIGI, pB = -BIGI, nF = BIGI, nB = BIGI;
    #pragma unroll
    for (int w = 0; w < 4; ++w) {
        unsigned long long v = (unsigned long long)mw[2 * w]
                             | ((unsigned long long)mw[2 * w + 1] << 32);
        unsigned long long g = ~v;
        int d = i - 64 * w;               // my bit position within this word
        unsigned long long bf = (d >= 63) ? v : ((d < 0) ? 0ull : (v & (~0ull >> (63 - d))));
        unsigned long long bb = (d >= 63) ? g : ((d < 0) ? 0ull : (g & (~0ull >> (63 - d))));
        if (bf) pF = 64 * w + 63 - __builtin_clzll(bf);   // w ascending => max
        if (bb) pB = 64 * w + 63 - __builtin_clzll(bb);
        unsigned long long af = (d <= 0) ? v : ((d > 63) ? 0ull : (v & (~0ull << d)));
        unsigned long long ab = (d <= 0) ? g : ((d > 63) ? 0ull : (g & (~0ull << d)));
        if (af) nF = min(nF, 64 * w + __builtin_ctzll(af));
        if (ab) nB = min(nB, 64 * w + __builtin_ctzll(ab));
    }
    int gF = min(min(i - pF, nF - i), 512);   // dist to nearest fg (0 if own fg)
    int gB = min(min(i - pB, nB - i), 512);   // dist to nearest bg
    bool isFg = (gF == 0);
    unsigned long long fgb = __ballot(isFg);

    float fF = (float)gF, fB = (float)gB;
    sF[j] = 1e30f; sF[2 * WW + j] = 1e30f; sF[WW + j] = fF * fF;
    sB[j] = 1e30f; sB[2 * WW + j] = 1e30f; sB[WW + j] = fB * fB;
    __syncthreads();

    // pruned exact 1D EDT over the OPPOSITE class (own-class dist is 0)
    const float* sp = isFg ? sB : sF;
    float m = isFg ? fB * fB : fF * fF;
    int idx = WW + j;
    for (int k = 1; k < WW; ++k) {
        float k2 = (float)(k * k);
        if (k2 >= m) break;               // exact termination (monotone offsets)
        m = fminf(m, sp[idx - k] + k2);
        m = fminf(m, sp[idx + k] + k2);
    }
    float dist = sqrtf(m);
    float phi = isFg ? -dist : dist;
    float prob = 1.0f / (1.0f + expf(-x));
    double sd = (double)(phi * prob);
    float mx = dist;

    #pragma unroll
    for (int off = 32; off; off >>= 1) {
        mx = fmaxf(mx, __shfl_down(mx, off));
        sd += __shfl_down(sd, off);
    }
    int wid = j >> 6;
    if ((j & 63) == 0) { wmax[wid] = mx; wsum[wid] = sd; wfg[wid] = (fgb != 0ull); }
    __syncthreads();
    if (j == 0) {
        part_max[row] = fmaxf(fmaxf(wmax[0], wmax[1]), fmaxf(wmax[2], wmax[3]));
        part_sum[row] = wsum[0] + wsum[1] + wsum[2] + wsum[3];
        part_fg[row] = wfg[0] | wfg[1] | wfg[2] | wfg[3];
    }
}

// k3: one block, 4 waves; wave w folds batches 2w and 2w+1.
__global__ void reduce_out(const float* __restrict__ part_max,
                           const double* __restrict__ part_sum,
                           const int* __restrict__ part_fg,
                           float* __restrict__ out) {
    __shared__ double terms[8];
    int tx = threadIdx.x;
    int wv = tx >> 6, l = tx & 63;
    #pragma unroll
    for (int q = 0; q < 2; ++q) {
        int b = wv * 2 + q;
        int base = b * HH;
        float mx = fmaxf(fmaxf(part_max[base + l], part_max[base + l + 64]),
                         fmaxf(part_max[base + l + 128], part_max[base + l + 192]));
        double sd = part_sum[base + l] + part_sum[base + l + 64]
                  + part_sum[base + l + 128] + part_sum[base + l + 192];
        int fg = part_fg[base + l] | part_fg[base + l + 64]
               | part_fg[base + l + 128] | part_fg[base + l + 192];
        #pragma unroll
        for (int off = 32; off; off >>= 1) {
            mx = fmaxf(mx, __shfl_down(mx, off));
            sd += __shfl_down(sd, off);
            fg |= __shfl_down(fg, off);
        }
        if (l == 0) terms[b] = fg ? sd / ((double)mx + 1e-8) : 0.0;
    }
    __syncthreads();
    if (tx == 0) {
        double t = 0.0;
        #pragma unroll
        for (int b = 0; b < BB; ++b) t += terms[b];
        out[0] = (float)(t / (double)NPIX);
    }
}

extern "C" void kernel_launch(void* const* d_in, const int* in_sizes, int n_in,
                              void* d_out, int out_size, void* d_ws, size_t ws_size,
                              hipStream_t stream) {
    const float* pred = (const float*)d_in[0];
    const int* tgt = (const int*)d_in[1];
    float* out = (float*)d_out;

    char* ws = (char*)d_ws;
    float* part_max = (float*)ws;                  // 2048 floats
    double* part_sum = (double*)(ws + 8192);       // 2048 doubles
    int* part_fg = (int*)(ws + 24576);             // 2048 ints
    unsigned* fg_words = (unsigned*)(ws + 32768);  // 16384 u32 (64 KB)

    maskbuild<<<64, 256, 0, stream>>>(tgt, fg_words);
    edt_row<<<NROWS, WW, 0, stream>>>(fg_words, pred, part_max, part_sum, part_fg);
    reduce_out<<<1, 256, 0, stream>>>(part_max, part_sum, part_fg, out);
}